// Round 18
// baseline (166.022 us; speedup 1.0000x reference)
//
#include <hip/hip_runtime.h>

// Path signature M=4, d=10, L=256, B=2048 — MFMA formulation, round 18.
// Math identical to r17 (absmax 10.5): b-row eliminated via b=a/2-r1/24-r2/12;
// K-rows per t: P=[a_hi,a_lo,r1,r2], Q_cell=[uw,uw,-w/24,-w/12], Q_vcol=[v,v,0,0].
// ROUND-18: producer/consumer WAVE SPECIALIZATION. Merge trick: pair (i,j) and
// cell (k,l)=(i,j) share chains, and cell w = vi*vj = r1 (free) -> ONE lane
// produces BOTH its P-row and Q-row. All production fits waves 0-1 (110 lanes);
// waves 2-5 are pure MFMA consumers (quadrants 16/12/12/9). Per-chunk critical
// path = max(produce, consume) instead of sum; dbuf overlaps ch/ch+1.
// Slot-major [slot][112][16B] (conflict-free b128), 1 barrier/chunk,
// produce<8>/<7> tail split, staging barrier before chain init (r12/13 lesson).

#define SIG 11110

typedef short bf16x8 __attribute__((ext_vector_type(8)));
typedef float f32x4  __attribute__((ext_vector_type(4)));

__device__ __forceinline__ unsigned cvt_pk2(float lo, float hi) {
    unsigned r;
    asm("v_cvt_pk_bf16_f32 %0, %1, %2" : "=v"(r) : "v"(lo), "v"(hi));
    return r;
}
// (bf16_hi(a) | bf16(a - hi)<<16), hi = truncated-to-bf16 (exact residual)
__device__ __forceinline__ unsigned split_pack(float a) {
    const float hi = __uint_as_float(__float_as_uint(a) & 0xFFFF0000u);
    return cvt_pk2(hi, a - hi);
}

template<int MI, int NI>
__device__ __forceinline__ void consume(const unsigned* __restrict__ Pb,
                                        const unsigned* __restrict__ Qb,
                                        int r0, int c0, int lane,
                                        f32x4 (&acc)[4][4]) {
    const int slot = lane >> 4, rr = lane & 15;
    bf16x8 Bf[NI];
    #pragma unroll
    for (int ni = 0; ni < NI; ++ni)
        Bf[ni] = *(const bf16x8*)(Qb + slot * 448 + (c0 + ni * 16 + rr) * 4);
    #pragma unroll
    for (int mi = 0; mi < MI; ++mi) {
        const bf16x8 Af = *(const bf16x8*)(Pb + slot * 448 + (r0 + mi * 16 + rr) * 4);
        #pragma unroll
        for (int ni = 0; ni < NI; ++ni)
            acc[mi][ni] = __builtin_amdgcn_mfma_f32_16x16x32_bf16(Af, Bf[ni], acc[mi][ni], 0, 0, 0);
    }
}

// NV = valid t's (8 for chunks 0..30, 7 for chunk 31).
template<int NV>
__device__ __forceinline__ void produce_t(int ch, const float* __restrict__ xs,
                                          unsigned* __restrict__ Pb,
                                          unsigned* __restrict__ Qb,
                                          bool isMerged, bool isVcol,
                                          int tid, int i1, int i2,
                                          float x0i, float xL2,
                                          float& c1, float& c2, float& Ds) {
    if (isMerged) {                      // pair (i,j) AND cell (i,j) on one lane
        unsigned p0 = 0, p1 = 0, s0 = 0, s1 = 0;
        #pragma unroll
        for (int tl = 0; tl < 8; ++tl) {
            unsigned pa, pr, pu, pw;
            if (tl < NV) {
                const float n1 = xs[(ch * 8 + tl + 1) * 10 + i1];
                const float n2 = xs[(ch * 8 + tl + 1) * 10 + i2];
                const float vi = n1 - c1, vj = n2 - c2;
                const float s1f = c1 - x0i;
                const float r1  = vi * vj;               // == cell w (shared!)
                const float r2  = s1f * vj;
                const float a   = fmaf(r1, 1.f/6.f, fmaf(r2, 0.5f, Ds));
                pa = split_pack(a);
                pr = cvt_pk2(r1, r2);
                const float m2 = fmaf(-0.5f, c2 + n2, xL2);   // R + v/2 factor
                const float uw = vi * m2;                      // u + w/2
                pu = cvt_pk2(uw, uw);
                pw = cvt_pk2(r1 * (-1.f/24.f), r1 * (-1.f/12.f));
                Ds += fmaf(0.5f, r1, r2);
                c1 = n1; c2 = n2;
            } else { pa = 0u; pr = 0u; pu = 0u; pw = 0u; }
            if ((tl & 1) == 0) { p0 = pa; p1 = pr; s0 = pu; s1 = pw; }
            else {
                *(uint4*)&Pb[(tl >> 1) * 448 + tid * 4] = make_uint4(p0, p1, pa, pr);
                *(uint4*)&Qb[(tl >> 1) * 448 + tid * 4] = make_uint4(s0, s1, pu, pw);
            }
        }
    } else if (isVcol) {                 // Q rows 100..109: v_t (S3 columns)
        unsigned q0 = 0;
        #pragma unroll
        for (int tl = 0; tl < 8; ++tl) {
            unsigned pv;
            if (tl < NV) {
                const float n1 = xs[(ch * 8 + tl + 1) * 10 + i1];
                pv = cvt_pk2(n1 - c1, n1 - c1);
                c1 = n1;
            } else pv = 0u;
            if ((tl & 1) == 0) q0 = pv;
            else *(uint4*)&Qb[(tl >> 1) * 448 + tid * 4] = make_uint4(q0, 0u, pv, 0u);
        }
    }
}

__global__ __launch_bounds__(384, 5)
void sig_mfma11(const float* __restrict__ xg, float* __restrict__ out) {
    __shared__ float    xs[2560];          // path [t*10+dim]           10240 B
    __shared__ unsigned Pl[2][4 * 448];    // dbuf [slot][112 rows][4w] 14336 B
    __shared__ unsigned Ql[2][4 * 448];    //                           14336 B

    const int tid  = threadIdx.x;
    const int b    = blockIdx.x;
    const int lane = tid & 63;
    const int wv   = tid >> 6;             // 0..5
    const float* __restrict__ xb = xg + (size_t)b * 2560;

    // stage path (coalesced) + zero pads (P rows 100..111, Q rows 110..111; both bufs)
    for (int e = tid; e < 2560; e += 384) xs[e] = xb[e];
    {   // 384 P-pad words exactly cover 384 threads
        const int buf = tid / 192, r = tid % 192, slot = r / 48, rem = r % 48;
        Pl[buf][slot * 448 + (100 + rem / 4) * 4 + (rem & 3)] = 0u;
    }
    if (tid < 64) {
        const int buf = tid / 32, r = tid % 32, slot = r / 8, rem = r % 8;
        Ql[buf][slot * 448 + (110 + rem / 4) * 4 + (rem & 3)] = 0u;
    }
    __syncthreads();   // staging visible BEFORE any xs read (r12/r13 lesson)

    // roles: waves 0-1 produce (merged pair+cell tid<100, vcol 100..109);
    //        waves 2-5 pure consumers.
    const bool isMerged = (tid < 100);
    const bool isVcol   = (tid >= 100) && (tid < 110);

    int i1 = 0, i2 = 0;
    if (isMerged)    { i1 = tid / 10;  i2 = tid - i1 * 10; }
    else if (isVcol) { i1 = tid - 100; i2 = i1; }

    float c1 = xs[i1], c2 = xs[i2];             // chains x_t[i1], x_t[i2]
    const float x0i = c1;
    const float xL2 = xs[2550 + i2];            // x_L[j] for the cell u-factor
    float Ds = 0.f;                             // running S2 (exact f32)

    f32x4 acc[4][4];
    #pragma unroll
    for (int mi = 0; mi < 4; ++mi)
        #pragma unroll
        for (int ni = 0; ni < 4; ++ni) acc[mi][ni] = (f32x4){0.f, 0.f, 0.f, 0.f};

    produce_t<8>(0, xs, Pl[0], Ql[0], isMerged, isVcol, tid, i1, i2, x0i, xL2, c1, c2, Ds);
    __syncthreads();

    for (int ch = 0; ch < 32; ++ch) {
        const unsigned* Pb = Pl[ch & 1];
        const unsigned* Qb = Ql[ch & 1];
        if      (wv == 2) consume<4, 4>(Pb, Qb,  0,  0, lane, acc);   // 16
        else if (wv == 3) consume<4, 3>(Pb, Qb,  0, 64, lane, acc);   // 12
        else if (wv == 4) consume<3, 4>(Pb, Qb, 64,  0, lane, acc);   // 12
        else if (wv == 5) consume<3, 3>(Pb, Qb, 64, 64, lane, acc);   //  9
        if (ch < 30)
            produce_t<8>(ch + 1, xs, Pl[(ch + 1) & 1], Ql[(ch + 1) & 1],
                         isMerged, isVcol, tid, i1, i2, x0i, xL2, c1, c2, Ds);
        else if (ch == 30)
            produce_t<7>(31, xs, Pl[1], Ql[1],
                         isMerged, isVcol, tid, i1, i2, x0i, xL2, c1, c2, Ds);
        __syncthreads();   // one barrier/chunk
    }

    // epilogue: [S1(10) | S2(100) | S3(1000) | S4(10000)]
    const size_t base = (size_t)b * SIG;
    if (tid < 10)  out[base + tid] = xs[2550 + tid] - xs[tid];   // S1 exact
    if (isMerged)  out[base + 10 + tid] = Ds;                    // S2 exact

    if (wv >= 2) {
        const int cw = wv - 2;
        const int r0 = (cw < 2) ? 0 : 64;
        const int c0 = (cw & 1) ? 64 : 0;
        #pragma unroll
        for (int mi = 0; mi < 4; ++mi) {
            #pragma unroll
            for (int ni = 0; ni < 4; ++ni) {
                #pragma unroll
                for (int r = 0; r < 4; ++r) {
                    const int m = r0 + mi * 16 + (lane >> 4) * 4 + r;
                    const int n = c0 + ni * 16 + (lane & 15);
                    if (m < 100) {
                        if (n < 100)      out[base + 1110 + m * 100 + n]         = acc[mi][ni][r];
                        else if (n < 110) out[base + 110  + m * 10  + (n - 100)] = acc[mi][ni][r];
                    }
                }
            }
        }
    }
}

extern "C" void kernel_launch(void* const* d_in, const int* in_sizes, int n_in,
                              void* d_out, int out_size, void* d_ws, size_t ws_size,
                              hipStream_t stream) {
    const float* x = (const float*)d_in[0];
    float* out = (float*)d_out;
    const int B = in_sizes[0] / 2560;   // 2048 batches, one block each
    sig_mfma11<<<B, 384, 0, stream>>>(x, out);
}